// Round 1
// baseline (1429.237 us; speedup 1.0000x reference)
//
#include <hip/hip_runtime.h>
#include <hip/hip_bf16.h>
#include <float.h>
#include <limits.h>

// Problem constants (fixed by reference setup_inputs)
#define BATCH 8
#define NN    4096
#define CC    256
#define KNN_K 4
#define NKE   (NN * KNN_K)   // edges per batch = N*k

// Tiling
#define TI  64               // rows per block
#define TJ  64               // cols per j-tile
#define TK  64               // k-chunk (floats)
#define LDA (TK + 4)         // LDS row stride, +4 float pad -> <=2-way bank aliasing (free)

// ---------------------------------------------------------------------------
// Kernel 1: inverse L2 norm per row. One 64-lane wave per row, 4 rows/block.
// ---------------------------------------------------------------------------
__global__ void knn_norm_kernel(const float* __restrict__ x, float* __restrict__ invn) {
    const int row  = blockIdx.x * 4 + (threadIdx.x >> 6);
    const int lane = threadIdx.x & 63;
    const float4 v = *(const float4*)(x + (size_t)row * CC + lane * 4);
    float ss = v.x * v.x + v.y * v.y + v.z * v.z + v.w * v.w;
    #pragma unroll
    for (int off = 32; off > 0; off >>= 1) ss += __shfl_down(ss, off, 64);
    if (lane == 0) invn[row] = 1.0f / sqrtf(ss);
}

// top-k ordering predicate matching jax.lax.top_k: value desc, ties -> smaller index
__device__ __forceinline__ bool knn_better(float v, int j, float v2, int j2) {
    return (v > v2) || (v == v2 && j < j2);
}

// ---------------------------------------------------------------------------
// Kernel 2: tiled sim + streaming top-4.
// Block = 256 threads = 16 row-groups x 16 col-groups; thread (rg,cg) owns
// rows {rg+16*ri} and cols {cg+16*ci} (strided -> conflict-free LDS reads).
// ---------------------------------------------------------------------------
__global__ __launch_bounds__(256) void knn_main_kernel(const float* __restrict__ x,
                                                       const float* __restrict__ invn,
                                                       float* __restrict__ out) {
    __shared__ __align__(16) float As[TI * LDA];   // 17408 B
    __shared__ __align__(16) float Bs[TJ * LDA];   // 17408 B  (34.8 KB total)

    const int tid = threadIdx.x;
    const int b   = blockIdx.x >> 6;     // 64 i-tiles per batch
    const int it  = blockIdx.x & 63;
    const int i0  = it * TI;
    const float* xb   = x    + (size_t)b * NN * CC;
    const float* invb = invn + (size_t)b * NN;
    const int rg = tid >> 4;             // 0..15
    const int cg = tid & 15;             // 0..15

    float vni[4];
    #pragma unroll
    for (int ri = 0; ri < 4; ++ri) vni[ri] = invb[i0 + rg + 16 * ri];

    // per-thread sorted top-4 (desc) per owned row
    float tv[4][4];
    int   tj[4][4];
    #pragma unroll
    for (int ri = 0; ri < 4; ++ri)
        #pragma unroll
        for (int s = 0; s < 4; ++s) { tv[ri][s] = -INFINITY; tj[ri][s] = INT_MAX; }

    for (int jt = 0; jt < NN / TJ; ++jt) {
        const int j0 = jt * TJ;
        float vnj[4];
        #pragma unroll
        for (int ci = 0; ci < 4; ++ci) vnj[ci] = invb[j0 + cg + 16 * ci];

        float acc[4][4];
        #pragma unroll
        for (int ri = 0; ri < 4; ++ri)
            #pragma unroll
            for (int ci = 0; ci < 4; ++ci) acc[ri][ci] = 0.0f;

        for (int kt = 0; kt < CC / TK; ++kt) {
            __syncthreads();   // protect prior-iter LDS reads before restaging
            // stage A-tile (rows i0..i0+63) and B-tile (rows j0..j0+63), k-chunk kt
            #pragma unroll
            for (int l = 0; l < 4; ++l) {
                const int p   = tid + 256 * l;     // float4 index 0..1023
                const int row = p >> 4;            // 16 float4 per row
                const int k4  = p & 15;
                const float4 av = *(const float4*)(xb + (size_t)(i0 + row) * CC + kt * TK + k4 * 4);
                const float4 bv = *(const float4*)(xb + (size_t)(j0 + row) * CC + kt * TK + k4 * 4);
                *(float4*)(As + row * LDA + k4 * 4) = av;
                *(float4*)(Bs + row * LDA + k4 * 4) = bv;
            }
            __syncthreads();
            #pragma unroll
            for (int k4 = 0; k4 < TK / 4; ++k4) {
                float4 a[4], bb[4];
                #pragma unroll
                for (int ri = 0; ri < 4; ++ri)
                    a[ri] = *(const float4*)(As + (rg + 16 * ri) * LDA + k4 * 4);
                #pragma unroll
                for (int ci = 0; ci < 4; ++ci)
                    bb[ci] = *(const float4*)(Bs + (cg + 16 * ci) * LDA + k4 * 4);
                #pragma unroll
                for (int ri = 0; ri < 4; ++ri)
                    #pragma unroll
                    for (int ci = 0; ci < 4; ++ci) {
                        acc[ri][ci] = fmaf(a[ri].x, bb[ci].x, acc[ri][ci]);
                        acc[ri][ci] = fmaf(a[ri].y, bb[ci].y, acc[ri][ci]);
                        acc[ri][ci] = fmaf(a[ri].z, bb[ci].z, acc[ri][ci]);
                        acc[ri][ci] = fmaf(a[ri].w, bb[ci].w, acc[ri][ci]);
                    }
            }
        }

        // top-k update for this j-tile (registers only)
        #pragma unroll
        for (int ri = 0; ri < 4; ++ri) {
            const int ig = i0 + rg + 16 * ri;
            #pragma unroll
            for (int ci = 0; ci < 4; ++ci) {
                const int jg = j0 + cg + 16 * ci;
                if (jg == ig) continue;  // diagonal = -inf in reference
                const float v = acc[ri][ci] * vni[ri] * vnj[ci];
                if (knn_better(v, jg, tv[ri][3], tj[ri][3])) {
                    tv[ri][3] = v; tj[ri][3] = jg;
                    #pragma unroll
                    for (int s = 3; s > 0; --s) {
                        if (knn_better(tv[ri][s], tj[ri][s], tv[ri][s - 1], tj[ri][s - 1])) {
                            const float fv = tv[ri][s]; tv[ri][s] = tv[ri][s - 1]; tv[ri][s - 1] = fv;
                            const int   fj = tj[ri][s]; tj[ri][s] = tj[ri][s - 1]; tj[ri][s - 1] = fj;
                        }
                    }
                }
            }
        }
    }

    // ---- merge per-row candidates across the 16 col-group threads ----
    __syncthreads();
    float* mv = As;            // 64 rows x stride 65 = 4160 floats (fits 4352)
    int*   mi = (int*)Bs;
    #pragma unroll
    for (int ri = 0; ri < 4; ++ri) {
        const int rl = rg + 16 * ri;
        #pragma unroll
        for (int s = 0; s < 4; ++s) {
            mv[rl * 65 + cg * 4 + s] = tv[ri][s];
            mi[rl * 65 + cg * 4 + s] = tj[ri][s];
        }
    }
    __syncthreads();

    if (tid < TI) {
        const int r  = tid;
        const int ig = i0 + r;
        float* rv = mv + r * 65;
        int*   rj = mi + r * 65;
        float bvv[4]; int bjj[4];
        for (int s = 0; s < 4; ++s) {
            float best_v = -INFINITY; int best_j = INT_MAX; int best_p = 0;
            for (int c = 0; c < 64; ++c) {
                if (knn_better(rv[c], rj[c], best_v, best_j)) {
                    best_v = rv[c]; best_j = rj[c]; best_p = c;
                }
            }
            bvv[s] = best_v; bjj[s] = best_j;
            rv[best_p] = -INFINITY; rj[best_p] = INT_MAX;
        }
        // outputs (all float32): edge_index (B,2,N*k) then edge_weight (B,N*k)
        float* o_src = out + (size_t)b * 2 * NKE;
        float* o_tgt = o_src + NKE;
        float* o_w   = out + (size_t)BATCH * 2 * NKE + (size_t)b * NKE;
        #pragma unroll
        for (int s = 0; s < 4; ++s) {
            o_src[ig * KNN_K + s] = (float)ig;
            o_tgt[ig * KNN_K + s] = (float)bjj[s];
            o_w[ig * KNN_K + s]   = bvv[s];
        }
    }
}

extern "C" void kernel_launch(void* const* d_in, const int* in_sizes, int n_in,
                              void* d_out, int out_size, void* d_ws, size_t ws_size,
                              hipStream_t stream) {
    const float* x   = (const float*)d_in[0];
    float*       out = (float*)d_out;
    float*       invn = (float*)d_ws;   // 8*4096 floats = 128 KB scratch

    knn_norm_kernel<<<(BATCH * NN) / 4, 256, 0, stream>>>(x, invn);
    knn_main_kernel<<<BATCH * (NN / TI), 256, 0, stream>>>(x, invn, out);
}

// Round 2
// 1367.880 us; speedup vs baseline: 1.0449x; 1.0449x over previous
//
#include <hip/hip_runtime.h>
#include <hip/hip_bf16.h>
#include <float.h>
#include <limits.h>

// Problem constants (fixed by reference setup_inputs)
#define BATCH 8
#define NN    4096
#define CC    256
#define KNN_K 4
#define NKE   (NN * KNN_K)

// Tiling: block = 512 threads (8 waves). Block tile 128 rows x 256 cols.
// Thread grid 16(rg) x 32(cg); per-thread register tile 8x8 (strided).
#define TI 128
#define TJ 256
#define TK 32
#define LW 36     // LDS row stride in words (32 + 4 pad); 144 B rows keep b128 alignment

// ---------------------------------------------------------------------------
// Kernel 1: inverse L2 norm per row. One 64-lane wave per row, 4 rows/block.
// ---------------------------------------------------------------------------
__global__ void knn_norm_kernel(const float* __restrict__ x, float* __restrict__ invn) {
    const int row  = blockIdx.x * 4 + (threadIdx.x >> 6);
    const int lane = threadIdx.x & 63;
    const float4 v = *(const float4*)(x + (size_t)row * CC + lane * 4);
    float ss = v.x * v.x + v.y * v.y + v.z * v.z + v.w * v.w;
    #pragma unroll
    for (int off = 32; off > 0; off >>= 1) ss += __shfl_down(ss, off, 64);
    if (lane == 0) invn[row] = 1.0f / sqrtf(ss);
}

// top-k ordering predicate matching jax.lax.top_k: value desc, ties -> smaller index
__device__ __forceinline__ bool knn_better(float v, int j, float v2, int j2) {
    return (v > v2) || (v == v2 && j < j2);
}

// insert candidate into sorted-descending top-4 (registers, fully unrolled)
__device__ __forceinline__ void knn_insert(float v, int j, float (&tv)[4], int (&tj)[4]) {
    if (knn_better(v, j, tv[3], tj[3])) {
        tv[3] = v; tj[3] = j;
        #pragma unroll
        for (int s = 3; s > 0; --s) {
            if (knn_better(tv[s], tj[s], tv[s - 1], tj[s - 1])) {
                float fv = tv[s]; tv[s] = tv[s - 1]; tv[s - 1] = fv;
                int   fj = tj[s]; tj[s] = tj[s - 1]; tj[s - 1] = fj;
            }
        }
    }
}

// ---------------------------------------------------------------------------
// Kernel 2: 128x256 tile, 8x8 per-thread, broadcast-heavy LDS reads,
// register-prefetch staging pipeline, shfl-butterfly top-4 merge.
// ---------------------------------------------------------------------------
__global__ __launch_bounds__(512, 2) void knn_main_kernel(const float* __restrict__ x,
                                                          const float* __restrict__ invn,
                                                          float* __restrict__ out) {
    __shared__ __align__(16) float As[TI * LW];   // 18.0 KB
    __shared__ __align__(16) float Bs[TJ * LW];   // 36.0 KB  (54 KB total)

    const int tid = threadIdx.x;
    const int b   = blockIdx.x >> 5;         // 32 i-tiles per batch
    const int it  = blockIdx.x & 31;
    const int i0  = it * TI;
    const float* xb   = x    + (size_t)b * NN * CC;
    const float* invb = invn + (size_t)b * NN;
    const int rg = tid >> 5;                 // 0..15 ; wave = {2 rg values} x all 32 cg
    const int cg = tid & 31;                 // 0..31

    float vni[8];
    #pragma unroll
    for (int ri = 0; ri < 8; ++ri) vni[ri] = invb[i0 + rg + 16 * ri];

    // per-thread sorted top-4 per owned row, kept for the whole kernel
    float tv[8][4];
    int   tjx[8][4];
    #pragma unroll
    for (int ri = 0; ri < 8; ++ri)
        #pragma unroll
        for (int s = 0; s < 4; ++s) { tv[ri][s] = -INFINITY; tjx[ri][s] = INT_MAX; }

    // staging decomposition: float4 id p -> row = p>>3, k4 = p&7 (8 float4 per row)
    const int sa_row0 = tid >> 3;            // A: rows  tid>>3 and +64
    const int sa_k4   = tid & 7;

    for (int jt = 0; jt < NN / TJ; ++jt) {   // 16 j-tiles
        const int j0 = jt * TJ;
        float vnj[8];
        #pragma unroll
        for (int ci = 0; ci < 8; ++ci) vnj[ci] = invb[j0 + cg + 32 * ci];

        float acc[8][8];
        #pragma unroll
        for (int ri = 0; ri < 8; ++ri)
            #pragma unroll
            for (int ci = 0; ci < 8; ++ci) acc[ri][ci] = 0.0f;

        // ---- prefetch k-chunk 0 into registers ----
        float4 pa[2], pb[4];
        #pragma unroll
        for (int l = 0; l < 2; ++l)
            pa[l] = *(const float4*)(xb + (size_t)(i0 + sa_row0 + 64 * l) * CC + sa_k4 * 4);
        #pragma unroll
        for (int l = 0; l < 4; ++l)
            pb[l] = *(const float4*)(xb + (size_t)(j0 + sa_row0 + 64 * l) * CC + sa_k4 * 4);

        for (int kt = 0; kt < CC / TK; ++kt) {   // 8 k-chunks
            __syncthreads();   // prior-iter LDS reads done before overwrite
            #pragma unroll
            for (int l = 0; l < 2; ++l)
                *(float4*)(As + (sa_row0 + 64 * l) * LW + sa_k4 * 4) = pa[l];
            #pragma unroll
            for (int l = 0; l < 4; ++l)
                *(float4*)(Bs + (sa_row0 + 64 * l) * LW + sa_k4 * 4) = pb[l];
            __syncthreads();

            // issue next chunk's global loads; latency overlaps compute below
            if (kt + 1 < CC / TK) {
                const int ko = (kt + 1) * TK + sa_k4 * 4;
                #pragma unroll
                for (int l = 0; l < 2; ++l)
                    pa[l] = *(const float4*)(xb + (size_t)(i0 + sa_row0 + 64 * l) * CC + ko);
                #pragma unroll
                for (int l = 0; l < 4; ++l)
                    pb[l] = *(const float4*)(xb + (size_t)(j0 + sa_row0 + 64 * l) * CC + ko);
            }

            #pragma unroll
            for (int k4 = 0; k4 < TK / 4; ++k4) {
                float4 a4[8], b4[8];
                #pragma unroll
                for (int ri = 0; ri < 8; ++ri)     // 2 distinct addrs/wave -> broadcast
                    a4[ri] = *(const float4*)(As + (rg + 16 * ri) * LW + k4 * 4);
                #pragma unroll
                for (int ci = 0; ci < 8; ++ci)     // 32 distinct addrs/wave, 4-phase min
                    b4[ci] = *(const float4*)(Bs + (cg + 32 * ci) * LW + k4 * 4);
                #pragma unroll
                for (int ri = 0; ri < 8; ++ri)
                    #pragma unroll
                    for (int ci = 0; ci < 8; ++ci) {
                        acc[ri][ci] = fmaf(a4[ri].x, b4[ci].x, acc[ri][ci]);
                        acc[ri][ci] = fmaf(a4[ri].y, b4[ci].y, acc[ri][ci]);
                        acc[ri][ci] = fmaf(a4[ri].z, b4[ci].z, acc[ri][ci]);
                        acc[ri][ci] = fmaf(a4[ri].w, b4[ci].w, acc[ri][ci]);
                    }
            }
        }

        // ---- top-k update for this j-tile (registers only) ----
        #pragma unroll
        for (int ri = 0; ri < 8; ++ri) {
            const int ig = i0 + rg + 16 * ri;
            #pragma unroll
            for (int ci = 0; ci < 8; ++ci) {
                const int jg = j0 + cg + 32 * ci;
                if (jg == ig) continue;            // diagonal = -inf in reference
                const float v = acc[ri][ci] * vni[ri] * vnj[ci];
                knn_insert(v, jg, tv[ri], tjx[ri]);
            }
        }
    }

    // ---- butterfly merge across the 32 cg lanes (same wave) ----
    #pragma unroll
    for (int m = 1; m <= 16; m <<= 1) {
        #pragma unroll
        for (int ri = 0; ri < 8; ++ri) {
            float pv[4]; int pj[4];
            #pragma unroll
            for (int s = 0; s < 4; ++s) {
                pv[s] = __shfl_xor(tv[ri][s],  m, 64);
                pj[s] = __shfl_xor(tjx[ri][s], m, 64);
            }
            #pragma unroll
            for (int s = 0; s < 4; ++s) knn_insert(pv[s], pj[s], tv[ri], tjx[ri]);
        }
    }

    // lane cg==0 of each rg holds the final top-4 for its 8 rows
    if (cg == 0) {
        float* o_src = out + (size_t)b * 2 * NKE;
        float* o_tgt = o_src + NKE;
        float* o_w   = out + (size_t)BATCH * 2 * NKE + (size_t)b * NKE;
        #pragma unroll
        for (int ri = 0; ri < 8; ++ri) {
            const int ig = i0 + rg + 16 * ri;
            #pragma unroll
            for (int s = 0; s < 4; ++s) {
                o_src[ig * KNN_K + s] = (float)ig;
                o_tgt[ig * KNN_K + s] = (float)tjx[ri][s];
                o_w[ig * KNN_K + s]   = tv[ri][s];
            }
        }
    }
}

extern "C" void kernel_launch(void* const* d_in, const int* in_sizes, int n_in,
                              void* d_out, int out_size, void* d_ws, size_t ws_size,
                              hipStream_t stream) {
    const float* x    = (const float*)d_in[0];
    float*       out  = (float*)d_out;
    float*       invn = (float*)d_ws;   // 8*4096 floats = 128 KB scratch

    knn_norm_kernel<<<(BATCH * NN) / 4, 256, 0, stream>>>(x, invn);
    knn_main_kernel<<<BATCH * (NN / TI), 512, 0, stream>>>(x, invn, out);
}

// Round 3
// 1333.917 us; speedup vs baseline: 1.0715x; 1.0255x over previous
//
#include <hip/hip_runtime.h>
#include <hip/hip_bf16.h>
#include <float.h>
#include <limits.h>

// Problem constants (fixed by reference setup_inputs)
#define BATCH 8
#define NN    4096
#define CC    256
#define KNN_K 4
#define NKE   (NN * KNN_K)

// Tiling: block = 512 threads (8 waves). Block tile 128 rows x 256 cols.
// Thread grid 16(rg) x 32(cg); per-thread register tile 8x8 (strided).
#define TI 128
#define TJ 256
#define TK 32
#define LW 36     // LDS row stride in words (32 + 4 pad); 144 B rows keep b128 alignment

// ---------------------------------------------------------------------------
// Kernel 1: inverse L2 norm per row. One 64-lane wave per row, 4 rows/block.
// ---------------------------------------------------------------------------
__global__ void knn_norm_kernel(const float* __restrict__ x, float* __restrict__ invn) {
    const int row  = blockIdx.x * 4 + (threadIdx.x >> 6);
    const int lane = threadIdx.x & 63;
    const float4 v = *(const float4*)(x + (size_t)row * CC + lane * 4);
    float ss = v.x * v.x + v.y * v.y + v.z * v.z + v.w * v.w;
    #pragma unroll
    for (int off = 32; off > 0; off >>= 1) ss += __shfl_down(ss, off, 64);
    if (lane == 0) invn[row] = 1.0f / sqrtf(ss);
}

// top-k ordering predicate matching jax.lax.top_k: value desc, ties -> smaller index
__device__ __forceinline__ bool knn_better(float v, int j, float v2, int j2) {
    return (v > v2) || (v == v2 && j < j2);
}

// insert candidate into sorted-descending top-4 (registers, fully unrolled)
__device__ __forceinline__ void knn_insert(float v, int j, float (&tv)[4], int (&tj)[4]) {
    if (knn_better(v, j, tv[3], tj[3])) {
        tv[3] = v; tj[3] = j;
        #pragma unroll
        for (int s = 3; s > 0; --s) {
            if (knn_better(tv[s], tj[s], tv[s - 1], tj[s - 1])) {
                float fv = tv[s]; tv[s] = tv[s - 1]; tv[s - 1] = fv;
                int   fj = tj[s]; tj[s] = tj[s - 1]; tj[s - 1] = fj;
            }
        }
    }
}

// ---------------------------------------------------------------------------
// Kernel 2: 128x256 tile, 8x8 per-thread, broadcast-heavy LDS reads,
// register-prefetch staging pipeline, shfl-butterfly top-4 merge.
// __launch_bounds__(512) with NO min-waves arg: a 512-thread block (8 waves,
// 2/SIMD) bounds VGPR at 256; (512,2) capped it at 128 -> 1.7GB spill traffic.
// ---------------------------------------------------------------------------
__global__ __launch_bounds__(512) void knn_main_kernel(const float* __restrict__ x,
                                                       const float* __restrict__ invn,
                                                       float* __restrict__ out) {
    __shared__ __align__(16) float As[TI * LW];   // 18.0 KB
    __shared__ __align__(16) float Bs[TJ * LW];   // 36.0 KB  (54 KB total)

    const int tid = threadIdx.x;
    const int b   = blockIdx.x >> 5;         // 32 i-tiles per batch
    const int it  = blockIdx.x & 31;
    const int i0  = it * TI;
    const float* xb   = x    + (size_t)b * NN * CC;
    const float* invb = invn + (size_t)b * NN;
    const int rg = tid >> 5;                 // 0..15 ; wave = {2 rg values} x all 32 cg
    const int cg = tid & 31;                 // 0..31

    float vni[8];
    #pragma unroll
    for (int ri = 0; ri < 8; ++ri) vni[ri] = invb[i0 + rg + 16 * ri];

    // per-thread sorted top-4 per owned row, kept for the whole kernel
    float tv[8][4];
    int   tjx[8][4];
    #pragma unroll
    for (int ri = 0; ri < 8; ++ri)
        #pragma unroll
        for (int s = 0; s < 4; ++s) { tv[ri][s] = -INFINITY; tjx[ri][s] = INT_MAX; }

    // staging decomposition: float4 id p -> row = p>>3, k4 = p&7 (8 float4 per row)
    const int sa_row0 = tid >> 3;            // A: rows  tid>>3 and +64
    const int sa_k4   = tid & 7;

    for (int jt = 0; jt < NN / TJ; ++jt) {   // 16 j-tiles
        const int j0 = jt * TJ;
        float vnj[8];
        #pragma unroll
        for (int ci = 0; ci < 8; ++ci) vnj[ci] = invb[j0 + cg + 32 * ci];

        float acc[8][8];
        #pragma unroll
        for (int ri = 0; ri < 8; ++ri)
            #pragma unroll
            for (int ci = 0; ci < 8; ++ci) acc[ri][ci] = 0.0f;

        // ---- prefetch k-chunk 0 into registers ----
        float4 pa[2], pb[4];
        #pragma unroll
        for (int l = 0; l < 2; ++l)
            pa[l] = *(const float4*)(xb + (size_t)(i0 + sa_row0 + 64 * l) * CC + sa_k4 * 4);
        #pragma unroll
        for (int l = 0; l < 4; ++l)
            pb[l] = *(const float4*)(xb + (size_t)(j0 + sa_row0 + 64 * l) * CC + sa_k4 * 4);

        for (int kt = 0; kt < CC / TK; ++kt) {   // 8 k-chunks
            __syncthreads();   // prior-iter LDS reads done before overwrite
            #pragma unroll
            for (int l = 0; l < 2; ++l)
                *(float4*)(As + (sa_row0 + 64 * l) * LW + sa_k4 * 4) = pa[l];
            #pragma unroll
            for (int l = 0; l < 4; ++l)
                *(float4*)(Bs + (sa_row0 + 64 * l) * LW + sa_k4 * 4) = pb[l];
            __syncthreads();

            // issue next chunk's global loads; latency overlaps compute below
            if (kt + 1 < CC / TK) {
                const int ko = (kt + 1) * TK + sa_k4 * 4;
                #pragma unroll
                for (int l = 0; l < 2; ++l)
                    pa[l] = *(const float4*)(xb + (size_t)(i0 + sa_row0 + 64 * l) * CC + ko);
                #pragma unroll
                for (int l = 0; l < 4; ++l)
                    pb[l] = *(const float4*)(xb + (size_t)(j0 + sa_row0 + 64 * l) * CC + ko);
            }

            #pragma unroll
            for (int k4 = 0; k4 < TK / 4; ++k4) {
                float4 b4[8];
                #pragma unroll
                for (int ci = 0; ci < 8; ++ci)     // 32 distinct addrs/wave, phase-clean
                    b4[ci] = *(const float4*)(Bs + (cg + 32 * ci) * LW + k4 * 4);
                #pragma unroll
                for (int ri = 0; ri < 8; ++ri) {   // 2 distinct addrs/wave -> broadcast
                    const float4 a4 = *(const float4*)(As + (rg + 16 * ri) * LW + k4 * 4);
                    #pragma unroll
                    for (int ci = 0; ci < 8; ++ci) {
                        acc[ri][ci] = fmaf(a4.x, b4[ci].x, acc[ri][ci]);
                        acc[ri][ci] = fmaf(a4.y, b4[ci].y, acc[ri][ci]);
                        acc[ri][ci] = fmaf(a4.z, b4[ci].z, acc[ri][ci]);
                        acc[ri][ci] = fmaf(a4.w, b4[ci].w, acc[ri][ci]);
                    }
                }
            }
        }

        // ---- top-k update for this j-tile (registers only) ----
        #pragma unroll
        for (int ri = 0; ri < 8; ++ri) {
            const int ig = i0 + rg + 16 * ri;
            #pragma unroll
            for (int ci = 0; ci < 8; ++ci) {
                const int jg = j0 + cg + 32 * ci;
                if (jg == ig) continue;            // diagonal = -inf in reference
                const float v = acc[ri][ci] * vni[ri] * vnj[ci];
                knn_insert(v, jg, tv[ri], tjx[ri]);
            }
        }
    }

    // ---- butterfly merge across the 32 cg lanes (same wave) ----
    #pragma unroll
    for (int m = 1; m <= 16; m <<= 1) {
        #pragma unroll
        for (int ri = 0; ri < 8; ++ri) {
            float pv[4]; int pj[4];
            #pragma unroll
            for (int s = 0; s < 4; ++s) {
                pv[s] = __shfl_xor(tv[ri][s],  m, 64);
                pj[s] = __shfl_xor(tjx[ri][s], m, 64);
            }
            #pragma unroll
            for (int s = 0; s < 4; ++s) knn_insert(pv[s], pj[s], tv[ri], tjx[ri]);
        }
    }

    // lane cg==0 of each rg holds the final top-4 for its 8 rows
    if (cg == 0) {
        float* o_src = out + (size_t)b * 2 * NKE;
        float* o_tgt = o_src + NKE;
        float* o_w   = out + (size_t)BATCH * 2 * NKE + (size_t)b * NKE;
        #pragma unroll
        for (int ri = 0; ri < 8; ++ri) {
            const int ig = i0 + rg + 16 * ri;
            #pragma unroll
            for (int s = 0; s < 4; ++s) {
                o_src[ig * KNN_K + s] = (float)ig;
                o_tgt[ig * KNN_K + s] = (float)tjx[ri][s];
                o_w[ig * KNN_K + s]   = tv[ri][s];
            }
        }
    }
}

extern "C" void kernel_launch(void* const* d_in, const int* in_sizes, int n_in,
                              void* d_out, int out_size, void* d_ws, size_t ws_size,
                              hipStream_t stream) {
    const float* x    = (const float*)d_in[0];
    float*       out  = (float*)d_out;
    float*       invn = (float*)d_ws;   // 8*4096 floats = 128 KB scratch

    knn_norm_kernel<<<(BATCH * NN) / 4, 256, 0, stream>>>(x, invn);
    knn_main_kernel<<<BATCH * (NN / TI), 512, 0, stream>>>(x, invn, out);
}